// Round 7
// baseline (419.977 us; speedup 1.0000x reference)
//
#include <hip/hip_runtime.h>
#include <hip/hip_bf16.h>

// VQ-VAE vector quantizer, MI355X (gfx950) — ROUND 13.
// Round-12 post-mortem: volatile did NOT fix k4f. Serial-chain model fits all rounds:
// dur ∝ cc_iters × loads/iter (r7 64x128=185, r10 64x128=185, r11 128x64=187,
// r12 64x64=113) — xv lives in SCRATCH (volatile forced the initial loads, but per-use
// scratch reloads are the same serial chain; r11 VGPR=60 < 64 proved no reg home).
// Fix: inline-asm global_load_dword for xv — asm outputs are opaque VGPR defs the
// compiler can NOT rematerialize, and at ~90 live regs under a 128 budget it has no
// reason to spill. Rule-#18 fence: asm s_waitcnt vmcnt(0) + sched_barrier(0) before use.
// New k4f shape: 256t blocks, 8 rows/block shared by 4 waves, wave owns a 64-code
// slice; grid 128 groups x 16 slices = 2048. Traffic (n/8)x8MB ~ 280MB L2/L3.
// Per-(row,code) math bitwise identical (8-fma chain m=0..7 stride 64, 6-level
// xor-reduce mask order, np_d32, fkey, atomicMin packed-min).
// k_prep/k2/k3/k4p/k4g/k5/k6 byte-identical to round 12 (single-variable experiment).

typedef _Float16 half8 __attribute__((ext_vector_type(8)));
typedef float floatx4 __attribute__((ext_vector_type(4)));
typedef unsigned long long u64;

#define N_ROWS 32768
#define DDIM   512
#define KCODES 4096
#define SCALE  1024.0f
#define SCALE2 1048576.0f     // 1024^2
#define TAUK   (250u << 12)
#define BIASF  524288.0f      // 2^19: s' = BIAS + ||w||^2*2^20 - 2*dot*2^20 in [147k, 901k] < 2^20
#define PAIR_CAP 8192
#define FULL_CAP 1024
#define LOSS_BLOCKS 8192

#define WH_OFF   0u
#define WSQS_OFF (4u*1024u*1024u)
#define SWW_OFF  (WSQS_OFF + 16384u)
#define SXX_OFF  (SWW_OFF + 16384u)
#define ST_K1    (SXX_OFF + 131072u)
#define ST_K2    (ST_K1 + 262144u)
#define ST_K3    (ST_K2 + 262144u)
#define IDX_OFF  (ST_K3 + 262144u)
#define PROW_OFF (IDX_OFF + 131072u)
#define PIDS_OFF (PROW_OFF + 4u*PAIR_CAP)
#define FROW_OFF (PIDS_OFF + 4u*PAIR_CAP)
#define FRES_OFF (FROW_OFF + 4u*FULL_CAP)
#define PCNT_OFF (FRES_OFF + 8u*FULL_CAP)
#define FCNT_OFF (PCNT_OFF + 256u)
#define LPART_OFF (FCNT_OFF + 256u)
#define USED_OFF (LPART_OFF + 4u*LOSS_BLOCKS)

__device__ __forceinline__ unsigned fkey(float f) {
    unsigned u = __float_as_uint(f);
    return (u & 0x80000000u) ? ~u : (u | 0x80000000u);
}

__device__ __forceinline__ float np_d32(float sxx, float dot32, float sww) {
    float t = sxx - 2.0f * dot32;
    return t + sww;
}

__device__ __forceinline__ unsigned uminu(unsigned a, unsigned b) { return a < b ? a : b; }
__device__ __forceinline__ unsigned umaxu(unsigned a, unsigned b) { return a > b ? a : b; }

__device__ __forceinline__ unsigned med3u(unsigned a, unsigned b, unsigned c) {
    unsigned r;
    asm("v_med3_u32 %0, %1, %2, %3" : "=v"(r) : "v"(a), "v"(b), "v"(c));
    return r;
}

typedef const __attribute__((address_space(1))) void* as1cv;
typedef __attribute__((address_space(3))) void* as3v;
__device__ __forceinline__ void gld_lds16(const void* g, void* l) {
    __builtin_amdgcn_global_load_lds((as1cv)g, (as3v)l, 16, 0, 0);
}

// opaque-register load: compiler cannot rematerialize or sink an asm-volatile output
#define XLOAD(dst, ptr) \
    asm volatile("global_load_dword %0, %1, off" : "=v"(dst) : "v"(ptr))

// ---------------- K_PREP: fused k0-init + k1-convert + k1b-wsq + k1c-sxx ----------------
__global__ void k_prep(const float* __restrict__ w, half8* __restrict__ wh,
                       float* __restrict__ wsqs, float* __restrict__ sww,
                       const float* __restrict__ x, float* __restrict__ sxx,
                       unsigned* __restrict__ used, unsigned* __restrict__ pcnt,
                       unsigned* __restrict__ fcnt, u64* __restrict__ fres) {
    const int bid = blockIdx.x;
    const int t = threadIdx.x;
    if (bid < 1024) {
        // ---- k1: codebook f32 -> fp16 (x1024), MFMA-fragment tiled ----
        int u = bid * 256 + t;
        int b = u >> 10, rem = u & 1023, c = rem >> 6, q = (rem >> 4) & 3, ri = rem & 15;
        int row = b * 16 + ri, d0 = c * 32 + q * 8;
        const float* p = w + (size_t)row * DDIM + d0;
        half8 h;
#pragma unroll
        for (int e = 0; e < 8; ++e) h[e] = (_Float16)(p[e] * SCALE);
        wh[u] = h;
    } else if (bid < 1088) {
        // ---- k1b: per-code ||w||^2 (f64) -> scaled f32 + np f32 ----
        int lane = t & 63;
        int wave = (bid - 1024) * 4 + (t >> 6);
        for (int k = wave; k < KCODES; k += 256) {
            const float* p = w + (size_t)k * DDIM;
            double s = 0.0;
#pragma unroll
            for (int m = 0; m < 8; ++m) { double v = p[lane + m * 64]; s += v * v; }
#pragma unroll
            for (int m = 1; m < 64; m <<= 1) s += __shfl_xor(s, m, 64);
            if (lane == 0) {
                sww[k]  = (float)s;
                wsqs[k] = (float)(s * (double)SCALE2);
            }
        }
    } else if (bid == 1088) {
        // ---- k0: init accumulators (ws poisoned each launch) ----
        for (int i = t; i < KCODES; i += 256) used[i] = 0u;
        for (int i = t; i < FULL_CAP; i += 256) fres[i] = ~0ull;
        if (t == 0) { *pcnt = 0u; *fcnt = 0u; }
    } else {
        // ---- k1c: per-row ||x||^2 — BITWISE numpy pairwise (D=512 tree) ----
#pragma clang fp contract(off)
        int lane = t & 63;
        int row = (bid - 1089) * 4 + (t >> 6);
        if (row >= N_ROWS) return;
        const float* p = x + (size_t)row * DDIM;
        int b = (lane >> 3) & 3, j = lane & 7;
        const float* q = p + b * 128 + j;
        float v0 = q[0];
        float s = v0 * v0;
#pragma unroll
        for (int i = 1; i < 16; ++i) { float v = q[8 * i]; float m = v * v; s = s + m; }
        s = s + __shfl_xor(s, 1, 64);
        s = s + __shfl_xor(s, 2, 64);
        s = s + __shfl_xor(s, 4, 64);
        s = s + __shfl_xor(s, 8, 64);
        s = s + __shfl_xor(s, 16, 64);
        if (lane == 0) sxx[row] = s;
    }
}

// ---------------- K2: fp16 MFMA GEMM-argmin, packed-key top-3 ----------------
__launch_bounds__(256, 2)
__global__ void k2_main(const float* __restrict__ x, const half8* __restrict__ wh,
                        const float* __restrict__ wsqs,
                        unsigned* __restrict__ sK1, unsigned* __restrict__ sK2,
                        unsigned* __restrict__ sK3) {
    __shared__ half8 w_lds[2][2048];   // 2 x 32 KiB double buffer (one 32-code phase each)
    __shared__ float wsq_lds[2048];    // split's ||w||^2 scaled, + BIAS folded in
    const int tid  = threadIdx.x;
    const int lane = tid & 63;
    const int wv   = tid >> 6;
    const int ks   = blockIdx.x & 1;
    const int rt   = blockIdx.x >> 1;
    const int r0   = rt * 128 + wv * 32;
    const int col  = lane & 15;
    const int q    = lane >> 4;

    const half8* wbase = wh + (size_t)ks * 131072;

    // prologue: stage phase 0 (wh layout == linear LDS copy, DMA pattern matches)
#pragma unroll
    for (int j = 0; j < 8; ++j)
        gld_lds16(wbase + j * 256 + tid, &w_lds[0][j * 256 + wv * 64]);

    for (int i = tid; i < 2048; i += 256) wsq_lds[i] = wsqs[ks * 2048 + i] + BIASF;

    // A fragments: 32 rows x 512 dims fp16 (resident for the whole kernel)
    half8 a[2][16];
#pragma unroll
    for (int i = 0; i < 2; ++i) {
        int row = r0 + i * 16 + col;
        const float* xr = x + (size_t)row * DDIM + q * 8;
#pragma unroll
        for (int c = 0; c < 16; ++c) {
            const float4* xp = (const float4*)(xr + c * 32);
            float4 lo = xp[0], hi = xp[1];
            half8 h;
            h[0]=(_Float16)lo.x; h[1]=(_Float16)lo.y; h[2]=(_Float16)lo.z; h[3]=(_Float16)lo.w;
            h[4]=(_Float16)hi.x; h[5]=(_Float16)hi.y; h[6]=(_Float16)hi.z; h[7]=(_Float16)hi.w;
            a[i][c] = h;
        }
    }

    // sorted packed-key triples per row-slot j (j = i*4+r): key = qdist<<12 | code
    unsigned K1[8], K2[8], K3[8];
#pragma unroll
    for (int j = 0; j < 8; ++j) { K1[j] = ~0u; K2[j] = ~0u; K3[j] = ~0u; }

    __syncthreads();   // drains vmcnt -> buf0 ready

    for (int ph = 0; ph < 64; ++ph) {
        const int buf = ph & 1;
        if (ph < 63) {
            const half8* gph = wbase + (size_t)(ph + 1) * 2048;
#pragma unroll
            for (int j = 0; j < 8; ++j)
                gld_lds16(gph + j * 256 + tid, &w_lds[buf ^ 1][j * 256 + wv * 64]);
        }
        floatx4 acc00 = {0.f,0.f,0.f,0.f}, acc01 = {0.f,0.f,0.f,0.f};
        floatx4 acc10 = {0.f,0.f,0.f,0.f}, acc11 = {0.f,0.f,0.f,0.f};
        __builtin_amdgcn_s_setprio(1);
#pragma unroll
        for (int c = 0; c < 16; ++c) {
            half8 b0 = w_lds[buf][c * 64 + lane];
            half8 b1 = w_lds[buf][1024 + c * 64 + lane];
            acc00 = __builtin_amdgcn_mfma_f32_16x16x32_f16(a[0][c], b0, acc00, 0, 0, 0);
            acc10 = __builtin_amdgcn_mfma_f32_16x16x32_f16(a[1][c], b0, acc10, 0, 0, 0);
            acc01 = __builtin_amdgcn_mfma_f32_16x16x32_f16(a[0][c], b1, acc01, 0, 0, 0);
            acc11 = __builtin_amdgcn_mfma_f32_16x16x32_f16(a[1][c], b1, acc11, 0, 0, 0);
        }
        __builtin_amdgcn_s_setprio(0);

        // tracker BEFORE barrier: acc-private VALU covers the prefetch-DMA drain
        const int cb = (ph << 5) + col;
        const unsigned code0 = (unsigned)(ks * 2048 + cb);
        const unsigned code1 = code0 + 16u;
        const float w0 = wsq_lds[cb];
        const float w1 = wsq_lds[cb + 16];
#pragma unroll
        for (int r = 0; r < 4; ++r) {
            {   float s0 = fmaf(-2048.0f, acc00[r], w0);
                unsigned key0 = ((unsigned)s0 << 12) | code0;
                unsigned n1 = uminu(K1[r], key0);
                unsigned n2 = med3u(K1[r], K2[r], key0);
                unsigned n3 = med3u(K2[r], K3[r], key0);
                float s1 = fmaf(-2048.0f, acc01[r], w1);
                unsigned key1 = ((unsigned)s1 << 12) | code1;
                K1[r] = uminu(n1, key1);
                K2[r] = med3u(n1, n2, key1);
                K3[r] = med3u(n2, n3, key1);
            }
            {   int j = 4 + r;
                float s0 = fmaf(-2048.0f, acc10[r], w0);
                unsigned key0 = ((unsigned)s0 << 12) | code0;
                unsigned n1 = uminu(K1[j], key0);
                unsigned n2 = med3u(K1[j], K2[j], key0);
                unsigned n3 = med3u(K2[j], K3[j], key0);
                float s1 = fmaf(-2048.0f, acc11[r], w1);
                unsigned key1 = ((unsigned)s1 << 12) | code1;
                K1[j] = uminu(n1, key1);
                K2[j] = med3u(n1, n2, key1);
                K3[j] = med3u(n2, n3, key1);
            }
        }
        __syncthreads();
    }

    // epilogue: merge sorted triples across the 16 col-lanes (masks 1,2,4,8)
#pragma unroll
    for (int j = 0; j < 8; ++j) {
        unsigned a1 = K1[j], a2 = K2[j], a3 = K3[j];
#pragma unroll
        for (int mask = 1; mask <= 8; mask <<= 1) {
            unsigned b1 = (unsigned)__shfl_xor((int)a1, mask, 64);
            unsigned b2 = (unsigned)__shfl_xor((int)a2, mask, 64);
            unsigned b3 = (unsigned)__shfl_xor((int)a3, mask, 64);
            unsigned r1 = uminu(a1, b1);
            unsigned r2 = uminu(umaxu(a1, b1), uminu(a2, b2));
            unsigned r3 = uminu(uminu(umaxu(a2, b1), umaxu(a1, b2)), uminu(a3, b3));
            a1 = r1; a2 = r2; a3 = r3;
        }
        if (col == 0) {
            int row = r0 + (j >> 2) * 16 + q * 4 + (j & 3);
            size_t o = (size_t)ks * N_ROWS + row;
            sK1[o] = a1; sK2[o] = a2; sK3[o] = a3;
        }
    }
}

// ---------------- K3: merge splits, default answer (f32 k), categorize ----------------
__global__ void k3_merge(const unsigned* __restrict__ sK1, const unsigned* __restrict__ sK2,
                         const unsigned* __restrict__ sK3,
                         int* __restrict__ idxArr, float* __restrict__ outk,
                         unsigned* __restrict__ pRow, unsigned* __restrict__ pIds,
                         unsigned* __restrict__ pCnt,
                         unsigned* __restrict__ fRow, unsigned* __restrict__ fCnt) {
    int row = blockIdx.x * 256 + threadIdx.x;
    unsigned a1 = sK1[row], a2 = sK2[row], a3 = sK3[row];
    unsigned b1 = sK1[N_ROWS + row], b2 = sK2[N_ROWS + row], b3 = sK3[N_ROWS + row];
    unsigned r1 = uminu(a1, b1);
    unsigned r2 = uminu(umaxu(a1, b1), uminu(a2, b2));
    unsigned r3 = uminu(uminu(umaxu(a2, b1), umaxu(a1, b2)), uminu(a3, b3));
    int i1 = (int)(r1 & 4095u);
    idxArr[row] = i1;
    outk[row] = (float)i1;
    if (r3 - r1 < TAUK) {
        unsigned p = atomicAdd(fCnt, 1u);
        if (p < FULL_CAP) fRow[p] = (unsigned)row;
    } else if (r2 - r1 < TAUK) {
        unsigned p = atomicAdd(pCnt, 1u);
        if (p < PAIR_CAP) {
            pRow[p] = (unsigned)row;
            pIds[p] = (r1 & 4095u) | ((r2 & 4095u) << 16);
        }
    }
}

// ---------------- K4p: pair rescore (np f32 semantics; f64 dots; stored np sxx) ----------------
__global__ void k4p_pair(const float* __restrict__ x, const float* __restrict__ w,
                         const float* __restrict__ sww, const float* __restrict__ sxx,
                         const unsigned* __restrict__ pRow, const unsigned* __restrict__ pIds,
                         const unsigned* __restrict__ pCnt,
                         int* __restrict__ idxArr, float* __restrict__ outk) {
    int n = (int)*pCnt; if (n > PAIR_CAP) n = PAIR_CAP;
    const int lane = threadIdx.x & 63;
    const int wave = blockIdx.x * 4 + (threadIdx.x >> 6);
    for (int i = wave; i < n; i += 512) {
        int row = (int)pRow[i] & (N_ROWS - 1);
        unsigned ids = pIds[i];
        int i1 = (int)(ids & 0xFFFFu) & (KCODES - 1);
        int i2 = (int)(ids >> 16) & (KCODES - 1);
        const float* xp = x + (size_t)row * DDIM;
        int code = (lane < 32) ? i1 : i2;
        const float* wp = w + (size_t)code * DDIM;
        int l32 = lane & 31;
        double dt = 0.0;
#pragma unroll
        for (int m = 0; m < 16; ++m) {
            int d = l32 + 32 * m;
            dt += (double)xp[d] * (double)wp[d];
        }
#pragma unroll
        for (int m = 1; m <= 16; m <<= 1) dt += __shfl_xor(dt, m, 64);
        double dot1 = __shfl(dt, 0, 64);
        double dot2 = __shfl(dt, 32, 64);
        if (lane == 0) {
            float sxx32 = sxx[row];
            float d1 = np_d32(sxx32, (float)dot1, sww[i1]);
            float d2 = np_d32(sxx32, (float)dot2, sww[i2]);
            bool take2 = (d2 < d1) || (d2 == d1 && i2 < i1);
            if (take2) { idxArr[row] = i2; outk[row] = (float)i2; }
        }
    }
}

// ---------------- K4f: full np-semantics rescan for crowded rows ----------------
// ROUND 13: inline-asm xv loads (opaque VGPR defs — no remat/sink/spill possible at
// ~90 live regs under 128 budget). 256t blocks, 8 rows/block shared by 4 waves, each
// wave owns a 64-code slice. Grid 128 groups x 16 slices = 2048 (idle blocks exit).
// Per-(row,code) math bitwise identical (fma order, xor-reduce order, np_d32, fkey).
__launch_bounds__(256, 2)
__global__ void k4f_full(const float* __restrict__ x, const float* __restrict__ w,
                         const float* __restrict__ sww, const float* __restrict__ sxx,
                         const unsigned* __restrict__ fRow, const unsigned* __restrict__ fCnt,
                         u64* __restrict__ fRes) {
    __shared__ int rws[8];
    __shared__ u64 sred[8];
    int n = (int)*fCnt; if (n > FULL_CAP) n = FULL_CAP;
    const int t = threadIdx.x, lane = t & 63, wv = t >> 6;     // 4 waves
    const int slice = blockIdx.x & 15, g = blockIdx.x >> 4;    // 128 groups x 16 slices
    if (g * 8 >= n) return;
    if (t < 8) {
        int fi = g * 8 + t;
        rws[t] = (int)fRow[fi < n ? fi : (n - 1)] & (N_ROWS - 1);
        sred[t] = ~0ull;
    }
    __syncthreads();

    int rowv[8];
#pragma unroll
    for (int r = 0; r < 8; ++r) rowv[r] = rws[r];

    // xv via opaque asm loads -> guaranteed VGPR residency (64 regs)
    float xv[8][8];
#pragma unroll
    for (int r = 0; r < 8; ++r) {
        const float* xp = x + (size_t)rowv[r] * DDIM + lane;
#pragma unroll
        for (int m = 0; m < 8; ++m) {
            XLOAD(xv[r][m], xp + 64 * m);
        }
    }
    asm volatile("s_waitcnt vmcnt(0)" ::: "memory");
    __builtin_amdgcn_sched_barrier(0);

    float sxxs[8];
#pragma unroll
    for (int r = 0; r < 8; ++r) sxxs[r] = sxx[rowv[r]];

    for (int cc = 0; cc < 64; ++cc) {
        int code = slice * 256 + wv * 64 + cc;
        const float* wp = w + (size_t)code * DDIM;
        float dt[8];
#pragma unroll
        for (int r = 0; r < 8; ++r) dt[r] = 0.f;
#pragma unroll
        for (int m = 0; m < 8; ++m) {
            float wvv = wp[lane + 64 * m];
#pragma unroll
            for (int r = 0; r < 8; ++r) dt[r] = fmaf(wvv, xv[r][m], dt[r]);
        }
#pragma unroll
        for (int r = 0; r < 8; ++r) {
#pragma unroll
            for (int mask = 1; mask < 64; mask <<= 1) dt[r] += __shfl_xor(dt[r], mask, 64);
        }
        if (lane == 0) {
            float swwc = sww[code];
#pragma unroll
            for (int r = 0; r < 8; ++r) {
                float dd = np_d32(sxxs[r], dt[r], swwc);
                u64 pk = ((u64)fkey(dd) << 32) | (unsigned)code;
                atomicMin(&sred[r], pk);
            }
        }
    }
    __syncthreads();
    if (t < 8) {
        int fi = g * 8 + t;
        if (fi < n) atomicMin(&fRes[fi], sred[t]);
    }
}

// ---------------- K4g: write back full-rescan winners ----------------
__global__ void k4g_write(const unsigned* __restrict__ fRow, const unsigned* __restrict__ fCnt,
                          const u64* __restrict__ fRes,
                          int* __restrict__ idxArr, float* __restrict__ outk) {
    int n = (int)*fCnt; if (n > FULL_CAP) n = FULL_CAP;
    for (int fi = threadIdx.x; fi < n; fi += 256) {
        int row = (int)fRow[fi] & (N_ROWS - 1);
        int code = (int)(unsigned)(fRes[fi] & 0xFFFFFFFFull) & (KCODES - 1);
        idxArr[row] = code;
        outk[row] = (float)code;
    }
}

// ---------------- K5: gather z_q (f32) + per-BLOCK loss partial (no global atomics) ----
__global__ void k5_gather(const float* __restrict__ x, const float* __restrict__ w,
                          const int* __restrict__ idxArr, float* __restrict__ outzq,
                          unsigned* __restrict__ used, float* __restrict__ lossPart) {
    __shared__ float lred[4];
    int g = blockIdx.x * 256 + threadIdx.x;
    int row = g >> 6, c8 = g & 63;
    int idx = idxArr[row] & (KCODES - 1);
    const float4* cb = (const float4*)(w + (size_t)idx * DDIM + c8 * 8);
    const float4* xp = (const float4*)(x + (size_t)row * DDIM + c8 * 8);
    float4* zq = (float4*)(outzq + (size_t)row * DDIM + c8 * 8);
    float4 c0 = cb[0], c1 = cb[1];
    float4 x0 = xp[0], x1 = xp[1];
    zq[0] = c0; zq[1] = c1;
    float part = 0.f;
    float d;
    d = x0.x - c0.x; part = fmaf(d, d, part);
    d = x0.y - c0.y; part = fmaf(d, d, part);
    d = x0.z - c0.z; part = fmaf(d, d, part);
    d = x0.w - c0.w; part = fmaf(d, d, part);
    d = x1.x - c1.x; part = fmaf(d, d, part);
    d = x1.y - c1.y; part = fmaf(d, d, part);
    d = x1.z - c1.z; part = fmaf(d, d, part);
    d = x1.w - c1.w; part = fmaf(d, d, part);
    if (c8 == 0) used[idx] = 1u;
#pragma unroll
    for (int m = 1; m < 64; m <<= 1) part += __shfl_xor(part, m, 64);
    int wv = threadIdx.x >> 6;
    if ((threadIdx.x & 63) == 0) lred[wv] = part;
    __syncthreads();
    if (threadIdx.x == 0)
        lossPart[blockIdx.x] = (lred[0] + lred[1]) + (lred[2] + lred[3]);
}

// ---------------- K6: loss partial sum + utilization + scalars (f32) ----------------
__global__ void k6_final(const unsigned* __restrict__ used, const float* __restrict__ lossPart,
                         float* __restrict__ out) {
    __shared__ int sred[256];
    __shared__ float fred[256];
    int t = threadIdx.x;
    int s = 0;
    for (int i = t; i < KCODES; i += 256) s += (int)used[i];
    float ls = 0.f;
    for (int i = t; i < LOSS_BLOCKS; i += 256) ls += lossPart[i];
    sred[t] = s; fred[t] = ls; __syncthreads();
    for (int off = 128; off > 0; off >>= 1) {
        if (t < off) { sred[t] += sred[t + off]; fred[t] += fred[t + off]; }
        __syncthreads();
    }
    if (t == 0) {
        size_t base = (size_t)N_ROWS * DDIM + N_ROWS;
        out[base]     = 0.25f * fred[0] / 16777216.0f;
        out[base + 1] = (float)sred[0] / 4096.0f;
    }
}

extern "C" void kernel_launch(void* const* d_in, const int* in_sizes, int n_in,
                              void* d_out, int out_size, void* d_ws, size_t ws_size,
                              hipStream_t stream) {
    (void)in_sizes; (void)n_in; (void)out_size; (void)ws_size;
    const float* x = (const float*)d_in[0];
    const float* w = (const float*)d_in[1];
    float* out = (float*)d_out;
    char* ws = (char*)d_ws;

    half8*    wh   = (half8*)(ws + WH_OFF);
    float*    wsqs = (float*)(ws + WSQS_OFF);
    float*    sww  = (float*)(ws + SWW_OFF);
    float*    sxx  = (float*)(ws + SXX_OFF);
    unsigned* sK1  = (unsigned*)(ws + ST_K1);
    unsigned* sK2  = (unsigned*)(ws + ST_K2);
    unsigned* sK3  = (unsigned*)(ws + ST_K3);
    int*      idxA = (int*)(ws + IDX_OFF);
    unsigned* pRow = (unsigned*)(ws + PROW_OFF);
    unsigned* pIds = (unsigned*)(ws + PIDS_OFF);
    unsigned* fRow = (unsigned*)(ws + FROW_OFF);
    u64*      fRes = (u64*)(ws + FRES_OFF);
    unsigned* pCnt = (unsigned*)(ws + PCNT_OFF);
    unsigned* fCnt = (unsigned*)(ws + FCNT_OFF);
    float*    lPart= (float*)(ws + LPART_OFF);
    unsigned* used = (unsigned*)(ws + USED_OFF);

    float* outk = out + (size_t)N_ROWS * DDIM;

    k_prep<<<9281, 256, 0, stream>>>(w, wh, wsqs, sww, x, sxx, used, pCnt, fCnt, fRes);
    k2_main<<<512, 256, 0, stream>>>(x, wh, wsqs, sK1, sK2, sK3);
    k3_merge<<<128, 256, 0, stream>>>(sK1, sK2, sK3, idxA, outk,
                                      pRow, pIds, pCnt, fRow, fCnt);
    k4p_pair<<<128, 256, 0, stream>>>(x, w, sww, sxx, pRow, pIds, pCnt, idxA, outk);
    k4f_full<<<2048, 256, 0, stream>>>(x, w, sww, sxx, fRow, fCnt, fRes);
    k4g_write<<<1, 256, 0, stream>>>(fRow, fCnt, fRes, idxA, outk);
    k5_gather<<<8192, 256, 0, stream>>>(x, w, idxA, out, used, lPart);
    k6_final<<<1, 256, 0, stream>>>(used, lPart, out);
}

// Round 8
// 384.788 us; speedup vs baseline: 1.0914x; 1.0914x over previous
//
#include <hip/hip_runtime.h>
#include <hip/hip_bf16.h>

// VQ-VAE vector quantizer, MI355X (gfx950) — ROUND 14.
// Round-13 post-mortem: asm-load k4f was NEUTRAL (414->420) — falsifies the residency
// theory for that shape. Across r7-r13 the ONLY fast k4f was round-8's (4 rows/block,
// xv[4][8]=32 regs, 64-slot strided loop): measured 84us inside the best total (398).
// r11 Occ=8.9% @8-wave blocks => fCnt ~ 64-96 rows: k4f is latency-structural, and
// r8's shape is the proven one. DECISION: restore r8's k4f VERBATIM (same math = same
// passing semantics). Second, orthogonal: k2 B-frag register double-buffer — MfmaUtil 41
// + VALUBusy 33 = pipes ALTERNATING (ds_read->lgkmcnt->MFMA chain); prefetching c+1's
// b0/b1 before c's MFMAs issues LDS reads under the MFMA shadow. Same addresses, same
// MFMA order => bitwise identical. k_prep/k3/k4p/k4g/k5/k6 byte-identical to round 13.

typedef _Float16 half8 __attribute__((ext_vector_type(8)));
typedef float floatx4 __attribute__((ext_vector_type(4)));
typedef unsigned long long u64;

#define N_ROWS 32768
#define DDIM   512
#define KCODES 4096
#define SCALE  1024.0f
#define SCALE2 1048576.0f     // 1024^2
#define TAUK   (250u << 12)
#define BIASF  524288.0f      // 2^19: s' = BIAS + ||w||^2*2^20 - 2*dot*2^20 in [147k, 901k] < 2^20
#define PAIR_CAP 8192
#define FULL_CAP 1024
#define LOSS_BLOCKS 8192

#define WH_OFF   0u
#define WSQS_OFF (4u*1024u*1024u)
#define SWW_OFF  (WSQS_OFF + 16384u)
#define SXX_OFF  (SWW_OFF + 16384u)
#define ST_K1    (SXX_OFF + 131072u)
#define ST_K2    (ST_K1 + 262144u)
#define ST_K3    (ST_K2 + 262144u)
#define IDX_OFF  (ST_K3 + 262144u)
#define PROW_OFF (IDX_OFF + 131072u)
#define PIDS_OFF (PROW_OFF + 4u*PAIR_CAP)
#define FROW_OFF (PIDS_OFF + 4u*PAIR_CAP)
#define FRES_OFF (FROW_OFF + 4u*FULL_CAP)
#define PCNT_OFF (FRES_OFF + 8u*FULL_CAP)
#define FCNT_OFF (PCNT_OFF + 256u)
#define LPART_OFF (FCNT_OFF + 256u)
#define USED_OFF (LPART_OFF + 4u*LOSS_BLOCKS)

__device__ __forceinline__ unsigned fkey(float f) {
    unsigned u = __float_as_uint(f);
    return (u & 0x80000000u) ? ~u : (u | 0x80000000u);
}

__device__ __forceinline__ float np_d32(float sxx, float dot32, float sww) {
    float t = sxx - 2.0f * dot32;
    return t + sww;
}

__device__ __forceinline__ unsigned uminu(unsigned a, unsigned b) { return a < b ? a : b; }
__device__ __forceinline__ unsigned umaxu(unsigned a, unsigned b) { return a > b ? a : b; }

__device__ __forceinline__ unsigned med3u(unsigned a, unsigned b, unsigned c) {
    unsigned r;
    asm("v_med3_u32 %0, %1, %2, %3" : "=v"(r) : "v"(a), "v"(b), "v"(c));
    return r;
}

typedef const __attribute__((address_space(1))) void* as1cv;
typedef __attribute__((address_space(3))) void* as3v;
__device__ __forceinline__ void gld_lds16(const void* g, void* l) {
    __builtin_amdgcn_global_load_lds((as1cv)g, (as3v)l, 16, 0, 0);
}

// ---------------- K_PREP: fused k0-init + k1-convert + k1b-wsq + k1c-sxx ----------------
__global__ void k_prep(const float* __restrict__ w, half8* __restrict__ wh,
                       float* __restrict__ wsqs, float* __restrict__ sww,
                       const float* __restrict__ x, float* __restrict__ sxx,
                       unsigned* __restrict__ used, unsigned* __restrict__ pcnt,
                       unsigned* __restrict__ fcnt, u64* __restrict__ fres) {
    const int bid = blockIdx.x;
    const int t = threadIdx.x;
    if (bid < 1024) {
        // ---- k1: codebook f32 -> fp16 (x1024), MFMA-fragment tiled ----
        int u = bid * 256 + t;
        int b = u >> 10, rem = u & 1023, c = rem >> 6, q = (rem >> 4) & 3, ri = rem & 15;
        int row = b * 16 + ri, d0 = c * 32 + q * 8;
        const float* p = w + (size_t)row * DDIM + d0;
        half8 h;
#pragma unroll
        for (int e = 0; e < 8; ++e) h[e] = (_Float16)(p[e] * SCALE);
        wh[u] = h;
    } else if (bid < 1088) {
        // ---- k1b: per-code ||w||^2 (f64) -> scaled f32 + np f32 ----
        int lane = t & 63;
        int wave = (bid - 1024) * 4 + (t >> 6);
        for (int k = wave; k < KCODES; k += 256) {
            const float* p = w + (size_t)k * DDIM;
            double s = 0.0;
#pragma unroll
            for (int m = 0; m < 8; ++m) { double v = p[lane + m * 64]; s += v * v; }
#pragma unroll
            for (int m = 1; m < 64; m <<= 1) s += __shfl_xor(s, m, 64);
            if (lane == 0) {
                sww[k]  = (float)s;
                wsqs[k] = (float)(s * (double)SCALE2);
            }
        }
    } else if (bid == 1088) {
        // ---- k0: init accumulators (ws poisoned each launch) ----
        for (int i = t; i < KCODES; i += 256) used[i] = 0u;
        for (int i = t; i < FULL_CAP; i += 256) fres[i] = ~0ull;
        if (t == 0) { *pcnt = 0u; *fcnt = 0u; }
    } else {
        // ---- k1c: per-row ||x||^2 — BITWISE numpy pairwise (D=512 tree) ----
#pragma clang fp contract(off)
        int lane = t & 63;
        int row = (bid - 1089) * 4 + (t >> 6);
        if (row >= N_ROWS) return;
        const float* p = x + (size_t)row * DDIM;
        int b = (lane >> 3) & 3, j = lane & 7;
        const float* q = p + b * 128 + j;
        float v0 = q[0];
        float s = v0 * v0;
#pragma unroll
        for (int i = 1; i < 16; ++i) { float v = q[8 * i]; float m = v * v; s = s + m; }
        s = s + __shfl_xor(s, 1, 64);
        s = s + __shfl_xor(s, 2, 64);
        s = s + __shfl_xor(s, 4, 64);
        s = s + __shfl_xor(s, 8, 64);
        s = s + __shfl_xor(s, 16, 64);
        if (lane == 0) sxx[row] = s;
    }
}

// ---------------- K2: fp16 MFMA GEMM-argmin, packed-key top-3 ----------------
// grid 512 = ks(2 splits) x rt(256 row-tiles of 128). 4 waves x 32 rows, 2 blocks/CU.
// 64 phases of 32 codes. ROUND 14: B-frag register double-buffer inside the c-loop —
// c+1's ds_reads issue before c's MFMAs (overlap LDS + MFMA pipes). Bitwise identical.
__launch_bounds__(256, 2)
__global__ void k2_main(const float* __restrict__ x, const half8* __restrict__ wh,
                        const float* __restrict__ wsqs,
                        unsigned* __restrict__ sK1, unsigned* __restrict__ sK2,
                        unsigned* __restrict__ sK3) {
    __shared__ half8 w_lds[2][2048];   // 2 x 32 KiB double buffer (one 32-code phase each)
    __shared__ float wsq_lds[2048];    // split's ||w||^2 scaled, + BIAS folded in
    const int tid  = threadIdx.x;
    const int lane = tid & 63;
    const int wv   = tid >> 6;
    const int ks   = blockIdx.x & 1;
    const int rt   = blockIdx.x >> 1;
    const int r0   = rt * 128 + wv * 32;
    const int col  = lane & 15;
    const int q    = lane >> 4;

    const half8* wbase = wh + (size_t)ks * 131072;

    // prologue: stage phase 0 (wh layout == linear LDS copy, DMA pattern matches)
#pragma unroll
    for (int j = 0; j < 8; ++j)
        gld_lds16(wbase + j * 256 + tid, &w_lds[0][j * 256 + wv * 64]);

    for (int i = tid; i < 2048; i += 256) wsq_lds[i] = wsqs[ks * 2048 + i] + BIASF;

    // A fragments: 32 rows x 512 dims fp16 (resident for the whole kernel)
    half8 a[2][16];
#pragma unroll
    for (int i = 0; i < 2; ++i) {
        int row = r0 + i * 16 + col;
        const float* xr = x + (size_t)row * DDIM + q * 8;
#pragma unroll
        for (int c = 0; c < 16; ++c) {
            const float4* xp = (const float4*)(xr + c * 32);
            float4 lo = xp[0], hi = xp[1];
            half8 h;
            h[0]=(_Float16)lo.x; h[1]=(_Float16)lo.y; h[2]=(_Float16)lo.z; h[3]=(_Float16)lo.w;
            h[4]=(_Float16)hi.x; h[5]=(_Float16)hi.y; h[6]=(_Float16)hi.z; h[7]=(_Float16)hi.w;
            a[i][c] = h;
        }
    }

    // sorted packed-key triples per row-slot j (j = i*4+r): key = qdist<<12 | code
    unsigned K1[8], K2[8], K3[8];
#pragma unroll
    for (int j = 0; j < 8; ++j) { K1[j] = ~0u; K2[j] = ~0u; K3[j] = ~0u; }

    __syncthreads();   // drains vmcnt -> buf0 ready

    for (int ph = 0; ph < 64; ++ph) {
        const int buf = ph & 1;
        if (ph < 63) {
            const half8* gph = wbase + (size_t)(ph + 1) * 2048;
#pragma unroll
            for (int j = 0; j < 8; ++j)
                gld_lds16(gph + j * 256 + tid, &w_lds[buf ^ 1][j * 256 + wv * 64]);
        }
        floatx4 acc00 = {0.f,0.f,0.f,0.f}, acc01 = {0.f,0.f,0.f,0.f};
        floatx4 acc10 = {0.f,0.f,0.f,0.f}, acc11 = {0.f,0.f,0.f,0.f};
        __builtin_amdgcn_s_setprio(1);
        // register double-buffer of B: c+1's reads issue before c's MFMAs
        half8 nb0 = w_lds[buf][lane];
        half8 nb1 = w_lds[buf][1024 + lane];
#pragma unroll
        for (int c = 0; c < 16; ++c) {
            half8 b0 = nb0, b1 = nb1;
            if (c < 15) {
                nb0 = w_lds[buf][(c + 1) * 64 + lane];
                nb1 = w_lds[buf][1024 + (c + 1) * 64 + lane];
            }
            acc00 = __builtin_amdgcn_mfma_f32_16x16x32_f16(a[0][c], b0, acc00, 0, 0, 0);
            acc10 = __builtin_amdgcn_mfma_f32_16x16x32_f16(a[1][c], b0, acc10, 0, 0, 0);
            acc01 = __builtin_amdgcn_mfma_f32_16x16x32_f16(a[0][c], b1, acc01, 0, 0, 0);
            acc11 = __builtin_amdgcn_mfma_f32_16x16x32_f16(a[1][c], b1, acc11, 0, 0, 0);
        }
        __builtin_amdgcn_s_setprio(0);

        // tracker BEFORE barrier: acc-private VALU covers the prefetch-DMA drain
        const int cb = (ph << 5) + col;
        const unsigned code0 = (unsigned)(ks * 2048 + cb);
        const unsigned code1 = code0 + 16u;
        const float w0 = wsq_lds[cb];
        const float w1 = wsq_lds[cb + 16];
#pragma unroll
        for (int r = 0; r < 4; ++r) {
            {   float s0 = fmaf(-2048.0f, acc00[r], w0);
                unsigned key0 = ((unsigned)s0 << 12) | code0;
                unsigned n1 = uminu(K1[r], key0);
                unsigned n2 = med3u(K1[r], K2[r], key0);
                unsigned n3 = med3u(K2[r], K3[r], key0);
                float s1 = fmaf(-2048.0f, acc01[r], w1);
                unsigned key1 = ((unsigned)s1 << 12) | code1;
                K1[r] = uminu(n1, key1);
                K2[r] = med3u(n1, n2, key1);
                K3[r] = med3u(n2, n3, key1);
            }
            {   int j = 4 + r;
                float s0 = fmaf(-2048.0f, acc10[r], w0);
                unsigned key0 = ((unsigned)s0 << 12) | code0;
                unsigned n1 = uminu(K1[j], key0);
                unsigned n2 = med3u(K1[j], K2[j], key0);
                unsigned n3 = med3u(K2[j], K3[j], key0);
                float s1 = fmaf(-2048.0f, acc11[r], w1);
                unsigned key1 = ((unsigned)s1 << 12) | code1;
                K1[j] = uminu(n1, key1);
                K2[j] = med3u(n1, n2, key1);
                K3[j] = med3u(n2, n3, key1);
            }
        }
        __syncthreads();
    }

    // epilogue: merge sorted triples across the 16 col-lanes (masks 1,2,4,8)
#pragma unroll
    for (int j = 0; j < 8; ++j) {
        unsigned a1 = K1[j], a2 = K2[j], a3 = K3[j];
#pragma unroll
        for (int mask = 1; mask <= 8; mask <<= 1) {
            unsigned b1 = (unsigned)__shfl_xor((int)a1, mask, 64);
            unsigned b2 = (unsigned)__shfl_xor((int)a2, mask, 64);
            unsigned b3 = (unsigned)__shfl_xor((int)a3, mask, 64);
            unsigned r1 = uminu(a1, b1);
            unsigned r2 = uminu(umaxu(a1, b1), uminu(a2, b2));
            unsigned r3 = uminu(uminu(umaxu(a2, b1), umaxu(a1, b2)), uminu(a3, b3));
            a1 = r1; a2 = r2; a3 = r3;
        }
        if (col == 0) {
            int row = r0 + (j >> 2) * 16 + q * 4 + (j & 3);
            size_t o = (size_t)ks * N_ROWS + row;
            sK1[o] = a1; sK2[o] = a2; sK3[o] = a3;
        }
    }
}

// ---------------- K3: merge splits, default answer (f32 k), categorize ----------------
__global__ void k3_merge(const unsigned* __restrict__ sK1, const unsigned* __restrict__ sK2,
                         const unsigned* __restrict__ sK3,
                         int* __restrict__ idxArr, float* __restrict__ outk,
                         unsigned* __restrict__ pRow, unsigned* __restrict__ pIds,
                         unsigned* __restrict__ pCnt,
                         unsigned* __restrict__ fRow, unsigned* __restrict__ fCnt) {
    int row = blockIdx.x * 256 + threadIdx.x;
    unsigned a1 = sK1[row], a2 = sK2[row], a3 = sK3[row];
    unsigned b1 = sK1[N_ROWS + row], b2 = sK2[N_ROWS + row], b3 = sK3[N_ROWS + row];
    unsigned r1 = uminu(a1, b1);
    unsigned r2 = uminu(umaxu(a1, b1), uminu(a2, b2));
    unsigned r3 = uminu(uminu(umaxu(a2, b1), umaxu(a1, b2)), uminu(a3, b3));
    int i1 = (int)(r1 & 4095u);
    idxArr[row] = i1;
    outk[row] = (float)i1;
    if (r3 - r1 < TAUK) {
        unsigned p = atomicAdd(fCnt, 1u);
        if (p < FULL_CAP) fRow[p] = (unsigned)row;
    } else if (r2 - r1 < TAUK) {
        unsigned p = atomicAdd(pCnt, 1u);
        if (p < PAIR_CAP) {
            pRow[p] = (unsigned)row;
            pIds[p] = (r1 & 4095u) | ((r2 & 4095u) << 16);
        }
    }
}

// ---------------- K4p: pair rescore (np f32 semantics; f64 dots; stored np sxx) ----------------
__global__ void k4p_pair(const float* __restrict__ x, const float* __restrict__ w,
                         const float* __restrict__ sww, const float* __restrict__ sxx,
                         const unsigned* __restrict__ pRow, const unsigned* __restrict__ pIds,
                         const unsigned* __restrict__ pCnt,
                         int* __restrict__ idxArr, float* __restrict__ outk) {
    int n = (int)*pCnt; if (n > PAIR_CAP) n = PAIR_CAP;
    const int lane = threadIdx.x & 63;
    const int wave = blockIdx.x * 4 + (threadIdx.x >> 6);
    for (int i = wave; i < n; i += 512) {
        int row = (int)pRow[i] & (N_ROWS - 1);
        unsigned ids = pIds[i];
        int i1 = (int)(ids & 0xFFFFu) & (KCODES - 1);
        int i2 = (int)(ids >> 16) & (KCODES - 1);
        const float* xp = x + (size_t)row * DDIM;
        int code = (lane < 32) ? i1 : i2;
        const float* wp = w + (size_t)code * DDIM;
        int l32 = lane & 31;
        double dt = 0.0;
#pragma unroll
        for (int m = 0; m < 16; ++m) {
            int d = l32 + 32 * m;
            dt += (double)xp[d] * (double)wp[d];
        }
#pragma unroll
        for (int m = 1; m <= 16; m <<= 1) dt += __shfl_xor(dt, m, 64);
        double dot1 = __shfl(dt, 0, 64);
        double dot2 = __shfl(dt, 32, 64);
        if (lane == 0) {
            float sxx32 = sxx[row];
            float d1 = np_d32(sxx32, (float)dot1, sww[i1]);
            float d2 = np_d32(sxx32, (float)dot2, sww[i2]);
            bool take2 = (d2 < d1) || (d2 == d1 && i2 < i1);
            if (take2) { idxArr[row] = i2; outk[row] = (float)i2; }
        }
    }
}

// ---------------- K4f: full np-semantics rescan for crowded rows ----------------
// ROUND 14: restored VERBATIM from round 8 — the only k4f variant that measured fast
// (84us inside the 398us best total). 4 rows/group (xv[4][8]=32 regs, truly resident),
// 64 slots x 16 slices = grid 1024, strided g-loop. Math bitwise identical.
__launch_bounds__(256, 4)
__global__ void k4f_full(const float* __restrict__ x, const float* __restrict__ w,
                         const float* __restrict__ sww, const float* __restrict__ sxx,
                         const unsigned* __restrict__ fRow, const unsigned* __restrict__ fCnt,
                         u64* __restrict__ fRes) {
    __shared__ int rws[4];
    __shared__ u64 sred[4];
    int n = (int)*fCnt; if (n > FULL_CAP) n = FULL_CAP;
    const int t = threadIdx.x, lane = t & 63, wv = t >> 6;
    const int slice = blockIdx.x & 15, slot0 = blockIdx.x >> 4;   // 64 slots
    for (int g = slot0; g * 4 < n; g += 64) {
        if (t < 4) {
            int fi = g * 4 + t;
            rws[t] = (int)fRow[fi < n ? fi : (n - 1)] & (N_ROWS - 1);
            sred[t] = ~0ull;
        }
        __syncthreads();
        float xv[4][8];
        float sxxs[4];
#pragma unroll
        for (int r = 0; r < 4; ++r) {
            const float* xp = x + (size_t)rws[r] * DDIM;
#pragma unroll
            for (int m = 0; m < 8; ++m) xv[r][m] = xp[lane + 64 * m];
            sxxs[r] = sxx[rws[r]];
        }
        for (int cc = 0; cc < 64; ++cc) {
            int code = slice * 256 + wv * 64 + cc;
            const float* wp = w + (size_t)code * DDIM;
            float dt[4];
#pragma unroll
            for (int r = 0; r < 4; ++r) dt[r] = 0.f;
#pragma unroll
            for (int m = 0; m < 8; ++m) {
                float wvv = wp[lane + 64 * m];
#pragma unroll
                for (int r = 0; r < 4; ++r) dt[r] = fmaf(wvv, xv[r][m], dt[r]);
            }
#pragma unroll
            for (int r = 0; r < 4; ++r) {
#pragma unroll
                for (int mask = 1; mask < 64; mask <<= 1) dt[r] += __shfl_xor(dt[r], mask, 64);
            }
            if (lane == 0) {
                float swwc = sww[code];
#pragma unroll
                for (int r = 0; r < 4; ++r) {
                    float dd = np_d32(sxxs[r], dt[r], swwc);
                    u64 pk = ((u64)fkey(dd) << 32) | (unsigned)code;
                    atomicMin(&sred[r], pk);
                }
            }
        }
        __syncthreads();
        if (t < 4) {
            int fi = g * 4 + t;
            if (fi < n) atomicMin(&fRes[fi], sred[t]);
        }
        __syncthreads();
    }
}

// ---------------- K4g: write back full-rescan winners ----------------
__global__ void k4g_write(const unsigned* __restrict__ fRow, const unsigned* __restrict__ fCnt,
                          const u64* __restrict__ fRes,
                          int* __restrict__ idxArr, float* __restrict__ outk) {
    int n = (int)*fCnt; if (n > FULL_CAP) n = FULL_CAP;
    for (int fi = threadIdx.x; fi < n; fi += 256) {
        int row = (int)fRow[fi] & (N_ROWS - 1);
        int code = (int)(unsigned)(fRes[fi] & 0xFFFFFFFFull) & (KCODES - 1);
        idxArr[row] = code;
        outk[row] = (float)code;
    }
}

// ---------------- K5: gather z_q (f32) + per-BLOCK loss partial (no global atomics) ----
__global__ void k5_gather(const float* __restrict__ x, const float* __restrict__ w,
                          const int* __restrict__ idxArr, float* __restrict__ outzq,
                          unsigned* __restrict__ used, float* __restrict__ lossPart) {
    __shared__ float lred[4];
    int g = blockIdx.x * 256 + threadIdx.x;
    int row = g >> 6, c8 = g & 63;
    int idx = idxArr[row] & (KCODES - 1);
    const float4* cb = (const float4*)(w + (size_t)idx * DDIM + c8 * 8);
    const float4* xp = (const float4*)(x + (size_t)row * DDIM + c8 * 8);
    float4* zq = (float4*)(outzq + (size_t)row * DDIM + c8 * 8);
    float4 c0 = cb[0], c1 = cb[1];
    float4 x0 = xp[0], x1 = xp[1];
    zq[0] = c0; zq[1] = c1;
    float part = 0.f;
    float d;
    d = x0.x - c0.x; part = fmaf(d, d, part);
    d = x0.y - c0.y; part = fmaf(d, d, part);
    d = x0.z - c0.z; part = fmaf(d, d, part);
    d = x0.w - c0.w; part = fmaf(d, d, part);
    d = x1.x - c1.x; part = fmaf(d, d, part);
    d = x1.y - c1.y; part = fmaf(d, d, part);
    d = x1.z - c1.z; part = fmaf(d, d, part);
    d = x1.w - c1.w; part = fmaf(d, d, part);
    if (c8 == 0) used[idx] = 1u;
#pragma unroll
    for (int m = 1; m < 64; m <<= 1) part += __shfl_xor(part, m, 64);
    int wv = threadIdx.x >> 6;
    if ((threadIdx.x & 63) == 0) lred[wv] = part;
    __syncthreads();
    if (threadIdx.x == 0)
        lossPart[blockIdx.x] = (lred[0] + lred[1]) + (lred[2] + lred[3]);
}

// ---------------- K6: loss partial sum + utilization + scalars (f32) ----------------
__global__ void k6_final(const unsigned* __restrict__ used, const float* __restrict__ lossPart,
                         float* __restrict__ out) {
    __shared__ int sred[256];
    __shared__ float fred[256];
    int t = threadIdx.x;
    int s = 0;
    for (int i = t; i < KCODES; i += 256) s += (int)used[i];
    float ls = 0.f;
    for (int i = t; i < LOSS_BLOCKS; i += 256) ls += lossPart[i];
    sred[t] = s; fred[t] = ls; __syncthreads();
    for (int off = 128; off > 0; off >>= 1) {
        if (t < off) { sred[t] += sred[t + off]; fred[t] += fred[t + off]; }
        __syncthreads();
    }
    if (t == 0) {
        size_t base = (size_t)N_ROWS * DDIM + N_ROWS;
        out[base]     = 0.25f * fred[0] / 16777216.0f;
        out[base + 1] = (float)sred[0] / 4096.0f;
    }
}

extern "C" void kernel_launch(void* const* d_in, const int* in_sizes, int n_in,
                              void* d_out, int out_size, void* d_ws, size_t ws_size,
                              hipStream_t stream) {
    (void)in_sizes; (void)n_in; (void)out_size; (void)ws_size;
    const float* x = (const float*)d_in[0];
    const float* w = (const float*)d_in[1];
    float* out = (float*)d_out;
    char* ws = (char*)d_ws;

    half8*    wh   = (half8*)(ws + WH_OFF);
    float*    wsqs = (float*)(ws + WSQS_OFF);
    float*    sww  = (float*)(ws + SWW_OFF);
    float*    sxx  = (float*)(ws + SXX_OFF);
    unsigned* sK1  = (unsigned*)(ws + ST_K1);
    unsigned* sK2  = (unsigned*)(ws + ST_K2);
    unsigned* sK3  = (unsigned*)(ws + ST_K3);
    int*      idxA = (int*)(ws + IDX_OFF);
    unsigned* pRow = (unsigned*)(ws + PROW_OFF);
    unsigned* pIds = (unsigned*)(ws + PIDS_OFF);
    unsigned* fRow = (unsigned*)(ws + FROW_OFF);
    u64*      fRes = (u64*)(ws + FRES_OFF);
    unsigned* pCnt = (unsigned*)(ws + PCNT_OFF);
    unsigned* fCnt = (unsigned*)(ws + FCNT_OFF);
    float*    lPart= (float*)(ws + LPART_OFF);
    unsigned* used = (unsigned*)(ws + USED_OFF);

    float* outk = out + (size_t)N_ROWS * DDIM;

    k_prep<<<9281, 256, 0, stream>>>(w, wh, wsqs, sww, x, sxx, used, pCnt, fCnt, fRes);
    k2_main<<<512, 256, 0, stream>>>(x, wh, wsqs, sK1, sK2, sK3);
    k3_merge<<<128, 256, 0, stream>>>(sK1, sK2, sK3, idxA, outk,
                                      pRow, pIds, pCnt, fRow, fCnt);
    k4p_pair<<<128, 256, 0, stream>>>(x, w, sww, sxx, pRow, pIds, pCnt, idxA, outk);
    k4f_full<<<1024, 256, 0, stream>>>(x, w, sww, sxx, fRow, fCnt, fRes);
    k4g_write<<<1, 256, 0, stream>>>(fRow, fCnt, fRes, idxA, outk);
    k5_gather<<<8192, 256, 0, stream>>>(x, w, idxA, out, used, lPart);
    k6_final<<<1, 256, 0, stream>>>(used, lPart, out);
}